// Round 5
// baseline (114229.419 us; speedup 1.0000x reference)
//
#include <hip/hip_runtime.h>

typedef _Float16 f16;
typedef _Float16 f16x2 __attribute__((ext_vector_type(2)));
typedef _Float16 f16x8 __attribute__((ext_vector_type(8)));
typedef float    f32x4 __attribute__((ext_vector_type(4)));

// ---------------- static device scratch (avoids ws_size assumptions) --------
__device__ f16   g_Xpad [64u*1028u*512u];   // conv1 input (B,T+4,512): ch0-255 coarse, 256-511 fine(final)
__device__ f16   g_fseqA[64u*1024u*256u];   // fine sequence ping
__device__ f16   g_fseqB[64u*1024u*256u];   // fine sequence pong
__device__ float g_xg32 [64u*1024u*1024u];  // per-f-layer input projection, permuted gate order, fp32
__device__ f16   g_c2in [64u*1026u*256u];   // conv2 input (B,T+2,256), padded
__device__ f16   g_c3in [64u*1024u*128u];   // conv3 input (B,T,128)
__device__ f16   g_whhT2[5u*262144u];       // [L][g'][k] fp16, permuted rows g' = u*4+q
__device__ f16   g_wihB [3u*262144u];       // [l][g'][k] fp16, permuted gate rows (g' = u*4+q)
__device__ float g_biasP[3*1024];           // permuted bih+bhh for f1..f3
__device__ f16   g_B1   [256u*2560u];       // conv1 weight as GEMM B [oc][r*512+ic]
__device__ f16   g_B2   [128u*768u];        // conv2 weight as GEMM B [oc][r*256+ic]
__device__ float g_xg0  [2*64*1024];        // static xg for coarse/f0, permuted [u*4+q]
__device__ float g_cat512[64*512];          // [h, le]
__device__ float g_h    [64*256];
__device__ float g_feats[64*512];           // [coarse.mean, fine.mean]
__device__ float g_osc  [64*1024];
__device__ float g_smean[1024];
__device__ float g_cpar [64*4];             // raw cp sigmoid outputs
__device__ float g_enh  [64*1024];
// cross-block h exchange for the 4-way unit-split LSTM
__device__ float g_hx   [2][64][256];       // double-buffered h (fp32), [buf][batch][unit]
__device__ int   g_flags[5][64][16];        // per-phase per-batch flags (padded to 64B)

// ---------------- helpers ---------------------------------------------------
__device__ inline float fdot2f(f16x2 a, f16x2 b, float c) {
#if __has_builtin(__builtin_amdgcn_fdot2)
  return __builtin_amdgcn_fdot2(a, b, c, false);
#else
  return c + (float)a[0]*(float)b[0] + (float)a[1]*(float)b[1];
#endif
}
__device__ inline float sigm_fast(float x) { return 1.0f / (1.0f + __expf(-x)); }
__device__ inline float tanh_fast(float x) { float e = __expf(2.0f*x); return 1.0f - 2.0f/(e + 1.0f); }
__device__ inline float lrelu(float x) { return x < 0.0f ? 0.2f*x : x; }

// ---------------- weight prep ----------------------------------------------
// permuted row order g' = u*4+q  <->  original gate row g = q*256+u (q: i,f,g,o)
__global__ void __launch_bounds__(256) k_prep_whh(const float* cw, const float* f0w, const float* fw) {
  int bid = blockIdx.x;               // 5*1024
  int L = bid >> 10, g = bid & 1023, k = threadIdx.x;
  const float* src = (L == 0) ? cw : (L == 1) ? f0w : (fw + (size_t)(L-2)*262144u);
  int q = g >> 8, u = g & 255;
  int gp = u*4 + q;
  g_whhT2[(size_t)L*262144u + (size_t)gp*256u + k] = (f16)src[(size_t)g*256 + k];
}
__global__ void __launch_bounds__(256) k_prep_wih(const float* fwih, const float* fbih, const float* fbhh) {
  int bid = blockIdx.x;               // 3*1024
  int L = bid >> 10, gp = bid & 1023, k = threadIdx.x;
  int j = gp >> 2, q = gp & 3, g = q*256 + j;
  g_wihB[(size_t)L*262144u + (size_t)gp*256u + k] = (f16)fwih[(size_t)L*262144u + (size_t)g*256u + k];
  if (k == 0) g_biasP[L*1024 + gp] = fbih[L*1024 + g] + fbhh[L*1024 + g];
}
__global__ void __launch_bounds__(256) k_prep_c1(const float* w) {
  int idx = blockIdx.x*256 + threadIdx.x;        // 655360
  int oc = idx / 2560, rem = idx % 2560, r = rem / 512, ic = rem % 512;
  g_B1[idx] = (f16)w[(size_t)oc*2560 + (size_t)ic*5 + r];
}
__global__ void __launch_bounds__(256) k_prep_c2(const float* w) {
  int idx = blockIdx.x*256 + threadIdx.x;        // 98304
  int oc = idx / 768, rem = idx % 768, r = rem / 256, ic = rem % 256;
  g_B2[idx] = (f16)w[(size_t)oc*768 + (size_t)ic*3 + r];
}
__global__ void __launch_bounds__(256) k_zero() {
  int idx = blockIdx.x*256 + threadIdx.x;        // grid 660 -> 168960
  if (idx < 131072) {   // Xpad pad rows 0,1,1026,1027
    int b = idx >> 11, rem = idx & 2047, rr = rem >> 9, c = rem & 511;
    int row = (rr < 2) ? rr : 1024 + rr;
    g_Xpad[(size_t)b*526336u + (size_t)row*512u + c] = (f16)0.0f;
  } else if (idx < 163840) {  // c2in pad rows 0, 1025
    int i2 = idx - 131072;
    int b = i2 >> 9, rem = i2 & 511, rr = rem >> 8, c = rem & 255;
    int row = rr ? 1025 : 0;
    g_c2in[(size_t)b*262656u + (size_t)row*256u + c] = (f16)0.0f;
  } else if (idx < 163840 + 5*64*16) {  // sync flags: MUST be zeroed every launch (graph replay)
    ((int*)g_flags)[idx - 163840] = 0;
  }
}

// ---------------- small front-end ops ---------------------------------------
__global__ void __launch_bounds__(256) k_setup1(const float* z, const int* labels, const float* emb,
                                                const float* npw, const float* npb,
                                                const float* lg, const float* lb) {
  __shared__ float x[384];
  __shared__ float s1[256], s2[256];
  int b = blockIdx.x, tid = threadIdx.x;
  int lab = labels[b];
  for (int i = tid; i < 384; i += 256)
    x[i] = (i < 128) ? z[b*128 + i] : emb[lab*256 + (i - 128)];
  __syncthreads();
  float acc = npb[tid];
  for (int k = 0; k < 384; ++k) acc += npw[tid*384 + k]*x[k];
  s1[tid] = acc; s2[tid] = acc*acc; __syncthreads();
  for (int s = 128; s > 0; s >>= 1) { if (tid < s) { s1[tid]+=s1[tid+s]; s2[tid]+=s2[tid+s]; } __syncthreads(); }
  float m = s1[0]*(1.0f/256.0f), var = s2[0]*(1.0f/256.0f) - m*m;
  float hv = (acc - m)*(1.0f/sqrtf(var + 1e-5f))*lg[tid] + lb[tid];
  hv = lrelu(hv);
  g_h[b*256 + tid] = hv;
  g_cat512[b*512 + tid] = hv;
  g_cat512[b*512 + 256 + tid] = x[128 + tid];
}
__global__ void __launch_bounds__(1024) k_xg0(const float* cwih, const float* cbih, const float* cbhh,
                                              const float* fwih, const float* fbih, const float* fbhh) {
  int bid = blockIdx.x;               // 128 = layer*64+b
  int layer = bid >> 6, b = bid & 63;
  int gp = threadIdx.x, j = gp >> 2, q = gp & 3, g = q*256 + j;
  __shared__ float cat[512];
  if (gp < 512) cat[gp] = g_cat512[b*512 + gp];
  __syncthreads();
  const float* w = layer ? fwih : cwih;
  float acc = layer ? (fbih[g] + fbhh[g]) : (cbih[g] + cbhh[g]);
  for (int k = 0; k < 512; ++k) acc += w[(size_t)g*512 + k]*cat[k];
  g_xg0[(layer*64 + b)*1024 + gp] = acc;
}
__global__ void __launch_bounds__(256) k_osc(const float* w1, const float* b1v, const float* lg,
                                             const float* lb, const float* w2, const float* b2v) {
  __shared__ float hb[256], av[256], s1[256], s2[256];
  int b = blockIdx.x, tid = threadIdx.x;
  hb[tid] = g_h[b*256 + tid];
  __syncthreads();
  float acc = b1v[tid];
  for (int k = 0; k < 256; ++k) acc += w1[tid*256 + k]*hb[k];
  s1[tid] = acc; s2[tid] = acc*acc; __syncthreads();
  for (int s = 128; s > 0; s >>= 1) { if (tid < s) { s1[tid]+=s1[tid+s]; s2[tid]+=s2[tid+s]; } __syncthreads(); }
  float m = s1[0]*(1.0f/256.0f), var = s2[0]*(1.0f/256.0f) - m*m;
  av[tid] = lrelu((acc - m)*(1.0f/sqrtf(var + 1e-5f))*lg[tid] + lb[tid]);
  __syncthreads();
  for (int tt = tid; tt < 1024; tt += 256) {
    float o = b2v[tt];
    for (int i = 0; i < 256; ++i) o += w2[(size_t)tt*256 + i]*av[i];
    g_osc[b*1024 + tt] = tanhf(o);
  }
}
__global__ void __launch_bounds__(256) k_sinmean(const float* sw, const float* sb) {
  int tt = blockIdx.x*256 + threadIdx.x;   // grid 4
  const float F[6] = {0.19f, 0.21f, 0.23f, 0.25f, 0.27f, 0.29f};
  float tl = tt*(1.0f/1023.0f);
  float sc[12];
  for (int j = 0; j < 6; ++j) {
    float p = (6.2831853071795864f * tl) * F[j] * 1024.0f;
    sc[j] = sinf(p); sc[6 + j] = cosf(p);
  }
  float a = 0.0f;
  for (int i = 0; i < 128; ++i) {
    float s = sb[i];
    for (int j = 0; j < 12; ++j) s += sw[i*12 + j]*sc[j];
    a += s;
  }
  g_smean[tt] = a*(1.0f/128.0f);
}

// ---------------- LSTM core: 4-way unit-split, weights LDS-resident ---------
// grid 256 = split j (bid>>6) x batch b (bid&63). Block (j,b) owns units
// [64j,64j+64) = permuted rows [256j,256j+256), 128KB fully LDS-resident
// (row stride 258 f16 = odd-dword -> conflict-free b32 reads). Thread t
// computes row t's dot each step; threads 0..63 do the c/h update for their
// unit. Per-step h exchange across the 4 sibling blocks via agent-scope
// atomics + monotone flags (double-buffered g_hx; flags zeroed per launch).
// Co-residency: 133KB LDS => 1 block/CU => 256 blocks always all resident.
// phase: 0=coarse 1=f0 2=f1 3=f2 4=f3 (matches g_whhT2 L index).
__global__ void __launch_bounds__(256, 1) k_lstm4(int phase) {
  int bid = blockIdx.x;
  int j = bid >> 6, b = bid & 63;
  int t = threadIdx.x;
  __shared__ __align__(16) f16 wlds[256*258];
  __shared__ __align__(16) f16 hbuf[256];
  __shared__ float gbuf[256];
  const f16* Wrow = g_whhT2 + (size_t)phase*262144u + (size_t)(j*256)*256u;
  // coalesced fill: 128KB, thread t copies contiguous global octets
#pragma unroll 4
  for (int i = 0; i < 32; ++i) {
    int e = i*2048 + t*8;
    int r = e >> 8, k0 = e & 255;
    *(f16x8*)(&wlds[r*258 + k0]) = *(const f16x8*)(Wrow + e);
  }
  hbuf[t] = (f16)0.0f;
  int u = j*64 + t;                      // unit owned by thread t (t<64 only)
  float c0 = 0.0f, sum0 = 0.0f;
  f32x4 xgs = {0.f, 0.f, 0.f, 0.f};
  const f32x4* xp = nullptr;
  f32x4 xv = {0.f, 0.f, 0.f, 0.f};
  if (phase < 2) {
    if (t < 64) xgs = *(const f32x4*)(g_xg0 + (phase*64 + b)*1024 + j*256 + 4*t);
  } else {
    xp = (const f32x4*)(g_xg32 + (size_t)b*1048576u + (size_t)(j*256 + 4*t));
    if (t < 64) xv = xp[0];
  }
  f16* outp; int ostride;
  if (phase == 0)      { outp = g_Xpad + (size_t)b*526336u + 1024 + u;       ostride = 512; }
  else if (phase == 1) { outp = g_fseqA + (size_t)b*262144u + u;             ostride = 256; }
  else if (phase == 2) { outp = g_fseqB + (size_t)b*262144u + u;             ostride = 256; }
  else if (phase == 3) { outp = g_fseqA + (size_t)b*262144u + u;             ostride = 256; }
  else                 { outp = g_Xpad + (size_t)b*526336u + 1024 + 256 + u; ostride = 512; }
  int* flagp = &g_flags[phase][b][0];
  __syncthreads();
  for (int step = 0; step < 1024; ++step) {
    // --- dot: row t over k=0..255, LDS weights + broadcast h ---
    float a0 = 0.0f, a1 = 0.0f, a2 = 0.0f, a3 = 0.0f;
    const f16* wr = &wlds[t*258];
#pragma unroll
    for (int kb = 0; kb < 32; ++kb) {
      f16x8 hv = *(const f16x8*)(&hbuf[kb*8]);
      f16x2 h0 = __builtin_shufflevector(hv, hv, 0, 1);
      f16x2 h1 = __builtin_shufflevector(hv, hv, 2, 3);
      f16x2 h2 = __builtin_shufflevector(hv, hv, 4, 5);
      f16x2 h3 = __builtin_shufflevector(hv, hv, 6, 7);
      f16x2 w0 = *(const f16x2*)(wr + kb*8 + 0);
      f16x2 w1 = *(const f16x2*)(wr + kb*8 + 2);
      f16x2 w2 = *(const f16x2*)(wr + kb*8 + 4);
      f16x2 w3 = *(const f16x2*)(wr + kb*8 + 6);
      a0 = fdot2f(w0, h0, a0);
      a1 = fdot2f(w1, h1, a1);
      a2 = fdot2f(w2, h2, a2);
      a3 = fdot2f(w3, h3, a3);
    }
    gbuf[t] = (a0 + a1) + (a2 + a3);
    __syncthreads();
    // --- update (wave 0 only): gates -> c,h; publish h ---
    if (t < 64) {
      float ii = gbuf[4*t + 0], ff = gbuf[4*t + 1], gg = gbuf[4*t + 2], oo = gbuf[4*t + 3];
      if (phase < 2) { ii += xgs[0]; ff += xgs[1]; gg += xgs[2]; oo += xgs[3]; }
      else           { ii += xv[0];  ff += xv[1];  gg += xv[2];  oo += xv[3];  }
      ii = sigm_fast(ii); ff = sigm_fast(ff); gg = tanh_fast(gg); oo = sigm_fast(oo);
      c0 = ff*c0 + ii*gg;
      float h0 = oo*tanh_fast(c0); sum0 += h0;
      outp[(size_t)step*ostride] = (f16)h0;
      if (step < 1023) {
        __hip_atomic_store(&g_hx[(step + 1) & 1][b][u], h0,
                           __ATOMIC_RELAXED, __HIP_MEMORY_SCOPE_AGENT);
        __threadfence();   // one s_waitcnt for the whole wave's stores
      }
    }
    if (step == 1023) break;
    __syncthreads();
    if (t == 0)
      __hip_atomic_store(flagp + j, step + 1, __ATOMIC_RELEASE, __HIP_MEMORY_SCOPE_AGENT);
    // --- spin until all 4 sibling blocks published h(step+1) ---
    for (;;) {
      int v = __hip_atomic_load(flagp + (t & 3), __ATOMIC_ACQUIRE, __HIP_MEMORY_SCOPE_AGENT);
      if (__syncthreads_and(v > step)) break;
      __builtin_amdgcn_s_sleep(1);
    }
    // --- rebuild hbuf from fresh h; prefetch next xg ---
    float hf = __hip_atomic_load(&g_hx[(step + 1) & 1][b][t],
                                 __ATOMIC_RELAXED, __HIP_MEMORY_SCOPE_AGENT);
    hbuf[t] = (f16)hf;
    if (phase >= 2 && t < 64) xv = xp[(size_t)(step + 1)*256u];
    __syncthreads();
  }
  if (t < 64) {
    if (phase == 0) g_feats[b*512 + u]       = sum0*(1.0f/1024.0f);
    if (phase == 4) g_feats[b*512 + 256 + u] = sum0*(1.0f/1024.0f);
  }
}

// ---------------- generic fp16 MFMA GEMM (implicit conv / xg projection) ----
__global__ void __launch_bounds__(256) k_gemm(int which, int l,
                                              const float* cb, const float* bng, const float* bnb) {
  const f16* A; size_t a_bs; int a_rs, K, N; const f16* Bm; int mode;
  float* outF = nullptr; f16* outH = nullptr; size_t o_bs; int o_rs;
  const float* bias;
  if (which <= 1) {
    A = (which == 0) ? g_fseqA : g_fseqB; a_bs = 262144u; a_rs = 256; K = 256; N = 1024;
    Bm = g_wihB + (size_t)l*262144u; mode = 0; bias = g_biasP + l*1024;
    outF = g_xg32; o_bs = 1048576u; o_rs = 1024;
  } else if (which == 2) {
    A = g_Xpad; a_bs = 526336u; a_rs = 512; K = 2560; N = 256; Bm = g_B1; mode = 1; bias = cb;
    outH = g_c2in + 256; o_bs = 262656u; o_rs = 256;
  } else {
    A = g_c2in; a_bs = 262656u; a_rs = 256; K = 768; N = 128; Bm = g_B2; mode = 1; bias = cb;
    outH = g_c3in; o_bs = 131072u; o_rs = 128;
  }
  int tid = threadIdx.x, wave = tid >> 6, lane = tid & 63;
  int m0 = blockIdx.x*128, n0 = blockIdx.y*64;
  __shared__ __align__(16) f16 Asm[128*72];
  __shared__ __align__(16) f16 Bsm[64*72];
  f32x4 acc[2][4];
#pragma unroll
  for (int i = 0; i < 2; ++i)
#pragma unroll
    for (int j = 0; j < 4; ++j) { f32x4 zz = {0.f,0.f,0.f,0.f}; acc[i][j] = zz; }
  int ar = tid & 127, ac = (tid >> 7)*32;
  int mrow = m0 + ar, abb = mrow >> 10, att = mrow & 1023;
  const f16* aptr = A + (size_t)abb*a_bs + (size_t)att*a_rs + ac;
  int br = tid & 63, bc = (tid >> 6)*16;
  const f16* bptr = Bm + (size_t)(n0 + br)*K + bc;
  int nkb = K >> 6;
  for (int kb = 0; kb < nkb; ++kb) {
    f16x8 av0 = *(const f16x8*)(aptr + 0);
    f16x8 av1 = *(const f16x8*)(aptr + 8);
    f16x8 av2 = *(const f16x8*)(aptr + 16);
    f16x8 av3 = *(const f16x8*)(aptr + 24);
    f16x8 bv0 = *(const f16x8*)(bptr + 0);
    f16x8 bv1 = *(const f16x8*)(bptr + 8);
    aptr += 64; bptr += 64;
    __syncthreads();
    *(f16x8*)(&Asm[ar*72 + ac + 0])  = av0;
    *(f16x8*)(&Asm[ar*72 + ac + 8])  = av1;
    *(f16x8*)(&Asm[ar*72 + ac + 16]) = av2;
    *(f16x8*)(&Asm[ar*72 + ac + 24]) = av3;
    *(f16x8*)(&Bsm[br*72 + bc + 0])  = bv0;
    *(f16x8*)(&Bsm[br*72 + bc + 8])  = bv1;
    __syncthreads();
#pragma unroll
    for (int ks = 0; ks < 2; ++ks) {
      int ko = ks*32 + (lane >> 4)*8;
      f16x8 a0 = *(const f16x8*)(&Asm[(wave*32 + (lane & 15))*72 + ko]);
      f16x8 a1 = *(const f16x8*)(&Asm[(wave*32 + 16 + (lane & 15))*72 + ko]);
#pragma unroll
      for (int nt = 0; nt < 4; ++nt) {
        f16x8 bf = *(const f16x8*)(&Bsm[(nt*16 + (lane & 15))*72 + ko]);
        acc[0][nt] = __builtin_amdgcn_mfma_f32_16x16x32_f16(a0, bf, acc[0][nt], 0, 0, 0);
        acc[1][nt] = __builtin_amdgcn_mfma_f32_16x16x32_f16(a1, bf, acc[1][nt], 0, 0, 0);
      }
    }
  }
  const float bnc = 0.99999500003749969f;  // 1/sqrt(1+1e-5)
#pragma unroll
  for (int mt = 0; mt < 2; ++mt)
#pragma unroll
    for (int nt = 0; nt < 4; ++nt)
#pragma unroll
      for (int r = 0; r < 4; ++r) {
        int m_loc = wave*32 + mt*16 + (lane >> 4)*4 + r;
        int n = n0 + nt*16 + (lane & 15);
        int mg = m0 + m_loc, ob = mg >> 10, ot = mg & 1023;
        float v = acc[mt][nt][r];
        if (mode == 0) {
          v += bias[n];
          outF[(size_t)ob*o_bs + (size_t)ot*o_rs + n] = v;
        } else {
          v = (v + bias[n])*(bng[n]*bnc) + bnb[n];
          v = lrelu(v);
          outH[(size_t)ob*o_bs + (size_t)ot*o_rs + n] = (f16)v;
        }
      }
}

// ---------------- cp head / cardiac params ----------------------------------
__global__ void __launch_bounds__(128) k_cp(const float* w1, const float* b1v, const float* lg,
                                            const float* lb, const float* w2, const float* b2v) {
  __shared__ float ft[512], av[128], s1[128], s2[128];
  int b = blockIdx.x, tid = threadIdx.x;
  for (int i = tid; i < 512; i += 128) ft[i] = g_feats[b*512 + i];
  __syncthreads();
  float acc = b1v[tid];
  for (int k = 0; k < 512; ++k) acc += w1[tid*512 + k]*ft[k];
  s1[tid] = acc; s2[tid] = acc*acc; __syncthreads();
  for (int s = 64; s > 0; s >>= 1) { if (tid < s) { s1[tid]+=s1[tid+s]; s2[tid]+=s2[tid+s]; } __syncthreads(); }
  float m = s1[0]*(1.0f/128.0f), var = s2[0]*(1.0f/128.0f) - m*m;
  av[tid] = lrelu((acc - m)*(1.0f/sqrtf(var + 1e-5f))*lg[tid] + lb[tid]);
  __syncthreads();
  if (tid < 4) {
    float s = b2v[tid];
    for (int i = 0; i < 128; ++i) s += w2[tid*128 + i]*av[i];
    g_cpar[b*4 + tid] = 1.0f/(1.0f + expf(-s));
  }
}

// ---------------- conv3 + enhanced ------------------------------------------
__global__ void __launch_bounds__(256) k_enh(const float* w3, const float* b3) {
  int idx = blockIdx.x*256 + threadIdx.x;
  int b = idx >> 10, t = idx & 1023;
  const f16* xc = g_c3in + (size_t)idx*128u;
  bool hm = (t > 0), hp = (t < 1023);
  float pre = b3[0];
  for (int c = 0; c < 128; ++c) {
    float xm = hm ? (float)xc[c - 128] : 0.0f;
    float x0 = (float)xc[c];
    float xp = hp ? (float)xc[c + 128] : 0.0f;
    pre += xm*w3[c*3] + x0*w3[c*3 + 1] + xp*w3[c*3 + 2];
  }
  float base = tanhf(pre);
  float cp0 = g_cpar[b*4 + 0], cp1 = g_cpar[b*4 + 1], cp2 = g_cpar[b*4 + 2], cp3 = g_cpar[b*4 + 3];
  float freq  = 0.19f + 0.1f*cp0;
  float amp   = 1.0f + 2.0f*cp1;
  float phase = 6.2831853071795864f*cp2;
  float basel = -0.5f + cp3;
  float tl = t*(1.0f/1023.0f);
  float arg = ((6.2831853071795864f*freq)*1024.0f)*tl + phase;
  float card = amp*sinf(arg) + basel;
  g_enh[idx] = 0.1f*base + 0.1f*g_osc[idx] + 0.7f*card + 0.1f*g_smean[t];
}

__global__ void __launch_bounds__(256) k_out(const int* labels, const float* sw,
                                             const float* aw, const float* ab, float* out) {
  int idx = blockIdx.x*256 + threadIdx.x;
  int b = idx >> 10, t = idx & 1023;
  int lab = labels[b];
  float e = g_enh[idx], r;
  if (lab == 1) r = e;
  else if (lab == 2) r = sw[0]*e;
  else if (lab == 3) {
    float em = (t > 0)    ? g_enh[idx - 1] : 0.0f;
    float ep = (t < 1023) ? g_enh[idx + 1] : 0.0f;
    r = aw[0]*em + aw[1]*e + aw[2]*ep + ab[0];
  } else r = 0.0f;
  out[idx] = r;
}

// ---------------- launch -----------------------------------------------------
extern "C" void kernel_launch(void* const* d_in, const int* in_sizes, int n_in,
                              void* d_out, int out_size, void* d_ws, size_t ws_size,
                              hipStream_t stream) {
  const float* z       = (const float*)d_in[0];
  const int*   labels  = (const int*)  d_in[1];
  const float* emb     = (const float*)d_in[2];
  const float* np_w    = (const float*)d_in[3];
  const float* np_b    = (const float*)d_in[4];
  const float* np_ln_g = (const float*)d_in[5];
  const float* np_ln_b = (const float*)d_in[6];
  const float* c_wih   = (const float*)d_in[7];
  const float* c_whh   = (const float*)d_in[8];
  const float* c_bih   = (const float*)d_in[9];
  const float* c_bhh   = (const float*)d_in[10];
  const float* f0_wih  = (const float*)d_in[11];
  const float* f0_whh  = (const float*)d_in[12];
  const float* f0_bih  = (const float*)d_in[13];
  const float* f0_bhh  = (const float*)d_in[14];
  const float* f_wih   = (const float*)d_in[15];
  const float* f_whh   = (const float*)d_in[16];
  const float* f_bih   = (const float*)d_in[17];
  const float* f_bhh   = (const float*)d_in[18];
  const float* osc_w1  = (const float*)d_in[19];
  const float* osc_b1  = (const float*)d_in[20];
  const float* osc_ln_g= (const float*)d_in[21];
  const float* osc_ln_b= (const float*)d_in[22];
  const float* osc_w2  = (const float*)d_in[23];
  const float* osc_b2  = (const float*)d_in[24];
  const float* cp_w1   = (const float*)d_in[25];
  const float* cp_b1   = (const float*)d_in[26];
  const float* cp_ln_g = (const float*)d_in[27];
  const float* cp_ln_b = (const float*)d_in[28];
  const float* cp_w2   = (const float*)d_in[29];
  const float* cp_b2   = (const float*)d_in[30];
  const float* sin_w   = (const float*)d_in[31];
  const float* sin_b   = (const float*)d_in[32];
  const float* conv1_w = (const float*)d_in[33];
  const float* conv1_b = (const float*)d_in[34];
  const float* bn1_g   = (const float*)d_in[35];
  const float* bn1_b   = (const float*)d_in[36];
  const float* conv2_w = (const float*)d_in[37];
  const float* conv2_b = (const float*)d_in[38];
  const float* bn2_g   = (const float*)d_in[39];
  const float* bn2_b   = (const float*)d_in[40];
  const float* conv3_w = (const float*)d_in[41];
  const float* conv3_b = (const float*)d_in[42];
  const float* stress_w= (const float*)d_in[43];
  const float* amuse_w = (const float*)d_in[44];
  const float* amuse_b = (const float*)d_in[45];
  float* out = (float*)d_out;

  k_prep_whh<<<5120, 256, 0, stream>>>(c_whh, f0_whh, f_whh);
  k_prep_wih<<<3072, 256, 0, stream>>>(f_wih, f_bih, f_bhh);
  k_prep_c1 <<<2560, 256, 0, stream>>>(conv1_w);
  k_prep_c2 <<< 384, 256, 0, stream>>>(conv2_w);
  k_zero    <<< 660, 256, 0, stream>>>();
  k_setup1  <<<  64, 256, 0, stream>>>(z, labels, emb, np_w, np_b, np_ln_g, np_ln_b);
  k_xg0     <<< 128,1024, 0, stream>>>(c_wih, c_bih, c_bhh, f0_wih, f0_bih, f0_bhh);
  k_osc     <<<  64, 256, 0, stream>>>(osc_w1, osc_b1, osc_ln_g, osc_ln_b, osc_w2, osc_b2);
  k_sinmean <<<   4, 256, 0, stream>>>(sin_w, sin_b);

  k_lstm4   <<< 256, 256, 0, stream>>>(0);                      // coarse
  k_lstm4   <<< 256, 256, 0, stream>>>(1);                      // f0
  for (int l = 0; l < 3; ++l) {                                 // f1, f2, f3
    int which = (l == 1) ? 1 : 0;                               // input seq ping-pong
    k_gemm  <<<dim3(512,16), 256, 0, stream>>>(which, l, nullptr, nullptr, nullptr);
    k_lstm4 <<< 256, 256, 0, stream>>>(2 + l);
  }
  k_cp      <<<  64, 128, 0, stream>>>(cp_w1, cp_b1, cp_ln_g, cp_ln_b, cp_w2, cp_b2);
  k_gemm    <<<dim3(512, 4), 256, 0, stream>>>(2, 0, conv1_b, bn1_g, bn1_b);   // conv1
  k_gemm    <<<dim3(512, 2), 256, 0, stream>>>(3, 0, conv2_b, bn2_g, bn2_b);   // conv2
  k_enh     <<< 256, 256, 0, stream>>>(conv3_w, conv3_b);
  k_out     <<< 256, 256, 0, stream>>>(labels, stress_w, amuse_w, amuse_b, out);
}

// Round 6
// 38773.236 us; speedup vs baseline: 2.9461x; 2.9461x over previous
//
#include <hip/hip_runtime.h>

typedef _Float16 f16;
typedef _Float16 f16x2 __attribute__((ext_vector_type(2)));
typedef _Float16 f16x8 __attribute__((ext_vector_type(8)));
typedef float    f32x4 __attribute__((ext_vector_type(4)));

// ---------------- static device scratch (avoids ws_size assumptions) --------
__device__ f16   g_Xpad [64u*1028u*512u];   // conv1 input (B,T+4,512): ch0-255 coarse, 256-511 fine(final)
__device__ f16   g_fseqA[64u*1024u*256u];   // fine sequence ping
__device__ f16   g_fseqB[64u*1024u*256u];   // fine sequence pong
__device__ float g_xg32 [64u*1024u*1024u];  // per-f-layer input projection, permuted gate order, fp32
__device__ f16   g_c2in [64u*1026u*256u];   // conv2 input (B,T+2,256), padded
__device__ f16   g_c3in [64u*1024u*128u];   // conv3 input (B,T,128)
// whh chunked layout: [L][kb:8][(q*4+j8)*256 + u][kl:8]; k = kb*32+j8*8+kl, gate row = q*256+u
__device__ f16   g_whhT2[5u*262144u];
__device__ f16   g_wihB [3u*262144u];       // [l][g'][k] fp16, permuted gate rows (g' = u*4+q)
__device__ float g_biasP[3*1024];           // permuted bih+bhh for f1..f3
__device__ f16   g_B1   [256u*2560u];       // conv1 weight as GEMM B [oc][r*512+ic]
__device__ f16   g_B2   [128u*768u];        // conv2 weight as GEMM B [oc][r*256+ic]
__device__ float g_xg0  [2*64*1024];        // static xg for coarse/f0, permuted [u*4+q]
__device__ float g_cat512[64*512];          // [h, le]
__device__ float g_h    [64*256];
__device__ float g_feats[64*512];           // [coarse.mean, fine.mean]
__device__ float g_osc  [64*1024];
__device__ float g_smean[1024];
__device__ float g_cpar [64*4];             // raw cp sigmoid outputs
__device__ float g_enh  [64*1024];

// ---------------- helpers ---------------------------------------------------
__device__ inline float fdot2f(f16x2 a, f16x2 b, float c) {
#if __has_builtin(__builtin_amdgcn_fdot2)
  return __builtin_amdgcn_fdot2(a, b, c, false);
#else
  return c + (float)a[0]*(float)b[0] + (float)a[1]*(float)b[1];
#endif
}
__device__ inline float sigm_fast(float x) { return 1.0f / (1.0f + __expf(-x)); }
__device__ inline float tanh_fast(float x) { float e = __expf(2.0f*x); return 1.0f - 2.0f/(e + 1.0f); }
__device__ inline float lrelu(float x) { return x < 0.0f ? 0.2f*x : x; }

__device__ __forceinline__ void dot8x(f16x8 w, f16x8 h, float& a) {
  a = fdot2f(__builtin_shufflevector(w, w, 0, 1), __builtin_shufflevector(h, h, 0, 1), a);
  a = fdot2f(__builtin_shufflevector(w, w, 2, 3), __builtin_shufflevector(h, h, 2, 3), a);
  a = fdot2f(__builtin_shufflevector(w, w, 4, 5), __builtin_shufflevector(h, h, 4, 5), a);
  a = fdot2f(__builtin_shufflevector(w, w, 6, 7), __builtin_shufflevector(h, h, 6, 7), a);
}

// 16 *named* f16x8 vars per chunk — no arrays => no SROA alloca => no scratch
// (R2/R4 lesson: any >~512B per-thread array gets demoted to scratch).
#define DECL16(p) f16x8 p##0,p##1,p##2,p##3,p##4,p##5,p##6,p##7,p##8,p##9,p##10,p##11,p##12,p##13,p##14,p##15
#define GLOAD16(p, base) do { const f16x8* _wp = (const f16x8*)(base); \
  p##0=_wp[0];    p##1=_wp[256];  p##2=_wp[512];  p##3=_wp[768]; \
  p##4=_wp[1024]; p##5=_wp[1280]; p##6=_wp[1536]; p##7=_wp[1792]; \
  p##8=_wp[2048]; p##9=_wp[2304]; p##10=_wp[2560];p##11=_wp[2816]; \
  p##12=_wp[3072];p##13=_wp[3328];p##14=_wp[3584];p##15=_wp[3840]; } while (0)
// octet qj = q*4+j8 covers k=[kb*32+j8*8, +8) of gate q  ->  pairs with h octet j8, acc[q]
#define CHUNK16(p, hb, kb) do { \
  const f16x8* _hp = (const f16x8*)((hb) + (kb)*32); \
  f16x8 _h0=_hp[0], _h1=_hp[1], _h2=_hp[2], _h3=_hp[3]; \
  dot8x(p##0,_h0,acc[0]); dot8x(p##1,_h1,acc[0]); dot8x(p##2,_h2,acc[0]); dot8x(p##3,_h3,acc[0]); \
  dot8x(p##4,_h0,acc[1]); dot8x(p##5,_h1,acc[1]); dot8x(p##6,_h2,acc[1]); dot8x(p##7,_h3,acc[1]); \
  dot8x(p##8,_h0,acc[2]); dot8x(p##9,_h1,acc[2]); dot8x(p##10,_h2,acc[2]); dot8x(p##11,_h3,acc[2]); \
  dot8x(p##12,_h0,acc[3]); dot8x(p##13,_h1,acc[3]); dot8x(p##14,_h2,acc[3]); dot8x(p##15,_h3,acc[3]); \
} while (0)

// ---------------- weight prep ----------------------------------------------
__global__ void __launch_bounds__(256) k_prep_whh(const float* cw, const float* f0w, const float* fw) {
  int bid = blockIdx.x;               // 5*1024
  int L = bid >> 10, g = bid & 1023, k = threadIdx.x;
  const float* src = (L == 0) ? cw : (L == 1) ? f0w : (fw + (size_t)(L-2)*262144u);
  int q = g >> 8, u = g & 255;                  // gate, unit
  int kb = k >> 5, j8 = (k >> 3) & 3, kl = k & 7;
  float v = src[(size_t)g*256 + k];
  g_whhT2[(size_t)L*262144u + (size_t)kb*32768u + (size_t)((q*4 + j8)*256 + u)*8u + kl] = (f16)v;
}
__global__ void __launch_bounds__(256) k_prep_wih(const float* fwih, const float* fbih, const float* fbhh) {
  int bid = blockIdx.x;               // 3*1024
  int L = bid >> 10, gp = bid & 1023, k = threadIdx.x;
  int j = gp >> 2, q = gp & 3, g = q*256 + j;
  g_wihB[(size_t)L*262144u + (size_t)gp*256u + k] = (f16)fwih[(size_t)L*262144u + (size_t)g*256u + k];
  if (k == 0) g_biasP[L*1024 + gp] = fbih[L*1024 + g] + fbhh[L*1024 + g];
}
__global__ void __launch_bounds__(256) k_prep_c1(const float* w) {
  int idx = blockIdx.x*256 + threadIdx.x;        // 655360
  int oc = idx / 2560, rem = idx % 2560, r = rem / 512, ic = rem % 512;
  g_B1[idx] = (f16)w[(size_t)oc*2560 + (size_t)ic*5 + r];
}
__global__ void __launch_bounds__(256) k_prep_c2(const float* w) {
  int idx = blockIdx.x*256 + threadIdx.x;        // 98304
  int oc = idx / 768, rem = idx % 768, r = rem / 256, ic = rem % 256;
  g_B2[idx] = (f16)w[(size_t)oc*768 + (size_t)ic*3 + r];
}
__global__ void __launch_bounds__(256) k_zero() {
  int idx = blockIdx.x*256 + threadIdx.x;        // 163840
  if (idx < 131072) {   // Xpad pad rows 0,1,1026,1027
    int b = idx >> 11, rem = idx & 2047, rr = rem >> 9, c = rem & 511;
    int row = (rr < 2) ? rr : 1024 + rr;
    g_Xpad[(size_t)b*526336u + (size_t)row*512u + c] = (f16)0.0f;
  } else {              // c2in pad rows 0, 1025
    int i2 = idx - 131072;
    int b = i2 >> 9, rem = i2 & 511, rr = rem >> 8, c = rem & 255;
    int row = rr ? 1025 : 0;
    g_c2in[(size_t)b*262656u + (size_t)row*256u + c] = (f16)0.0f;
  }
}

// ---------------- small front-end ops ---------------------------------------
__global__ void __launch_bounds__(256) k_setup1(const float* z, const int* labels, const float* emb,
                                                const float* npw, const float* npb,
                                                const float* lg, const float* lb) {
  __shared__ float x[384];
  __shared__ float s1[256], s2[256];
  int b = blockIdx.x, tid = threadIdx.x;
  int lab = labels[b];
  for (int i = tid; i < 384; i += 256)
    x[i] = (i < 128) ? z[b*128 + i] : emb[lab*256 + (i - 128)];
  __syncthreads();
  float acc = npb[tid];
  for (int k = 0; k < 384; ++k) acc += npw[tid*384 + k]*x[k];
  s1[tid] = acc; s2[tid] = acc*acc; __syncthreads();
  for (int s = 128; s > 0; s >>= 1) { if (tid < s) { s1[tid]+=s1[tid+s]; s2[tid]+=s2[tid+s]; } __syncthreads(); }
  float m = s1[0]*(1.0f/256.0f), var = s2[0]*(1.0f/256.0f) - m*m;
  float hv = (acc - m)*(1.0f/sqrtf(var + 1e-5f))*lg[tid] + lb[tid];
  hv = lrelu(hv);
  g_h[b*256 + tid] = hv;
  g_cat512[b*512 + tid] = hv;
  g_cat512[b*512 + 256 + tid] = x[128 + tid];
}
__global__ void __launch_bounds__(1024) k_xg0(const float* cwih, const float* cbih, const float* cbhh,
                                              const float* fwih, const float* fbih, const float* fbhh) {
  int bid = blockIdx.x;               // 128 = layer*64+b
  int layer = bid >> 6, b = bid & 63;
  int gp = threadIdx.x, j = gp >> 2, q = gp & 3, g = q*256 + j;
  __shared__ float cat[512];
  if (gp < 512) cat[gp] = g_cat512[b*512 + gp];
  __syncthreads();
  const float* w = layer ? fwih : cwih;
  float acc = layer ? (fbih[g] + fbhh[g]) : (cbih[g] + cbhh[g]);
  for (int k = 0; k < 512; ++k) acc += w[(size_t)g*512 + k]*cat[k];
  g_xg0[(layer*64 + b)*1024 + gp] = acc;
}
__global__ void __launch_bounds__(256) k_osc(const float* w1, const float* b1v, const float* lg,
                                             const float* lb, const float* w2, const float* b2v) {
  __shared__ float hb[256], av[256], s1[256], s2[256];
  int b = blockIdx.x, tid = threadIdx.x;
  hb[tid] = g_h[b*256 + tid];
  __syncthreads();
  float acc = b1v[tid];
  for (int k = 0; k < 256; ++k) acc += w1[tid*256 + k]*hb[k];
  s1[tid] = acc; s2[tid] = acc*acc; __syncthreads();
  for (int s = 128; s > 0; s >>= 1) { if (tid < s) { s1[tid]+=s1[tid+s]; s2[tid]+=s2[tid+s]; } __syncthreads(); }
  float m = s1[0]*(1.0f/256.0f), var = s2[0]*(1.0f/256.0f) - m*m;
  av[tid] = lrelu((acc - m)*(1.0f/sqrtf(var + 1e-5f))*lg[tid] + lb[tid]);
  __syncthreads();
  for (int tt = tid; tt < 1024; tt += 256) {
    float o = b2v[tt];
    for (int i = 0; i < 256; ++i) o += w2[(size_t)tt*256 + i]*av[i];
    g_osc[b*1024 + tt] = tanhf(o);
  }
}
__global__ void __launch_bounds__(256) k_sinmean(const float* sw, const float* sb) {
  int tt = blockIdx.x*256 + threadIdx.x;   // grid 4
  const float F[6] = {0.19f, 0.21f, 0.23f, 0.25f, 0.27f, 0.29f};
  float tl = tt*(1.0f/1023.0f);
  float sc[12];
  for (int j = 0; j < 6; ++j) {
    float p = (6.2831853071795864f * tl) * F[j] * 1024.0f;
    sc[j] = sinf(p); sc[6 + j] = cosf(p);
  }
  float a = 0.0f;
  for (int i = 0; i < 128; ++i) {
    float s = sb[i];
    for (int j = 0; j < 12; ++j) s += sw[i*12 + j]*sc[j];
    a += s;
  }
  g_smean[tt] = a*(1.0f/128.0f);
}

// ---------------- LSTM core (1 batch / block, 256 threads) -------------------
// thread t owns hidden unit t; c in a register. Weight chunks (64KB each):
//   kb0,kb1 -> 32 NAMED f16x8 register variables (128 VGPRs, loaded once)
//   kb2,kb3 -> LDS (128 KB, copied once)
//   kb4..7  -> streamed per step, 2-deep pipeline through named buffers
// One __syncthreads per step (h ping-pong). No cross-block sync (R5 lesson),
// no DMA builtins (R3 lesson), no per-thread weight arrays (R2/R4 lesson).
__global__ void __launch_bounds__(256, 1) k_lstmA() {
  int bid = blockIdx.x;              // 128: [0,64) coarse, [64,128) f0
  int layer = bid >> 6, b = bid & 63;
  int t = threadIdx.x;
  const f16* Wc = g_whhT2 + (size_t)layer*262144u;
  __shared__ __align__(16) f16 wlds[65536];
  __shared__ __align__(16) f16 hbuf[2][256];
#pragma unroll 8
  for (int i = 0; i < 32; ++i) {                 // LDS <- kb2,kb3
    int e = i*2048 + t*8;
    *(f16x8*)(wlds + e) = *(const f16x8*)(Wc + 65536 + e);
  }
  DECL16(r); DECL16(s);
  GLOAD16(r, Wc + t*8);                          // kb0 resident
  GLOAD16(s, Wc + 32768 + t*8);                  // kb1 resident
  const f16* wt4 = Wc + 4*32768 + t*8;
  const f16* wt5 = Wc + 5*32768 + t*8;
  const f16* wt6 = Wc + 6*32768 + t*8;
  const f16* wt7 = Wc + 7*32768 + t*8;
  f32x4 xvA = *(const f32x4*)(g_xg0 + (layer*64 + b)*1024 + 4*t);
  hbuf[0][t] = (f16)0.0f;
  float c0 = 0.0f, sum0 = 0.0f;
  __syncthreads();
  f16* outp; int ostride;
  if (layer == 0) { outp = g_Xpad + (size_t)b*526336u + 1024 + t; ostride = 512; }
  else            { outp = g_fseqA + (size_t)b*262144u + t;       ostride = 256; }
  int cur = 0;
#pragma unroll 1
  for (int step = 0; step < 1024; ++step) {
    float acc[4] = {xvA[0], xvA[1], xvA[2], xvA[3]};
    const f16* hb = &hbuf[cur][0];
    DECL16(sa); DECL16(sb);
    GLOAD16(sa, wt4);
    CHUNK16(r, hb, 0);
    CHUNK16(s, hb, 1);
    { DECL16(la); GLOAD16(la, wlds + t*8);         CHUNK16(la, hb, 2); }
    { DECL16(lb); GLOAD16(lb, wlds + 32768 + t*8); CHUNK16(lb, hb, 3); }
    GLOAD16(sb, wt5);
    CHUNK16(sa, hb, 4);
    GLOAD16(sa, wt6);
    CHUNK16(sb, hb, 5);
    GLOAD16(sb, wt7);
    CHUNK16(sa, hb, 6);
    CHUNK16(sb, hb, 7);
    float ii = sigm_fast(acc[0]), ff = sigm_fast(acc[1]);
    float gg = tanh_fast(acc[2]), oo = sigm_fast(acc[3]);
    c0 = ff*c0 + ii*gg;
    float h0 = oo*tanh_fast(c0); sum0 += h0;
    hbuf[cur ^ 1][t] = (f16)h0;
    outp[(size_t)step*ostride] = (f16)h0;
    __syncthreads();
    cur ^= 1;
  }
  if (layer == 0) g_feats[b*512 + t] = sum0*(1.0f/1024.0f);
}

__global__ void __launch_bounds__(256, 1) k_lstmF(int l) {   // l=0..2 -> fine layers f1..f3
  int b = blockIdx.x;               // 64
  int t = threadIdx.x;
  const f16* Wc = g_whhT2 + (size_t)(2 + l)*262144u;
  __shared__ __align__(16) f16 wlds[65536];
  __shared__ __align__(16) f16 hbuf[2][256];
#pragma unroll 8
  for (int i = 0; i < 32; ++i) {                 // LDS <- kb2,kb3
    int e = i*2048 + t*8;
    *(f16x8*)(wlds + e) = *(const f16x8*)(Wc + 65536 + e);
  }
  DECL16(r); DECL16(s);
  GLOAD16(r, Wc + t*8);
  GLOAD16(s, Wc + 32768 + t*8);
  const f16* wt4 = Wc + 4*32768 + t*8;
  const f16* wt5 = Wc + 5*32768 + t*8;
  const f16* wt6 = Wc + 6*32768 + t*8;
  const f16* wt7 = Wc + 7*32768 + t*8;
  const f32x4* xp = (const f32x4*)(g_xg32 + (size_t)b*1048576u + 4*t);
  hbuf[0][t] = (f16)0.0f;
  float c0 = 0.0f, sum0 = 0.0f;
  __syncthreads();
  f16* outp; int ostride;
  if (l == 0)      { outp = g_fseqB + (size_t)b*262144u + t; ostride = 256; }
  else if (l == 1) { outp = g_fseqA + (size_t)b*262144u + t; ostride = 256; }
  else             { outp = g_Xpad + (size_t)b*526336u + 1024 + 256 + t; ostride = 512; }
  int cur = 0;
#pragma unroll 1
  for (int step = 0; step < 1024; ++step) {
    f32x4 xv = xp[(size_t)step*256u];
    float acc[4] = {0.0f, 0.0f, 0.0f, 0.0f};
    const f16* hb = &hbuf[cur][0];
    DECL16(sa); DECL16(sb);
    GLOAD16(sa, wt4);
    CHUNK16(r, hb, 0);
    CHUNK16(s, hb, 1);
    { DECL16(la); GLOAD16(la, wlds + t*8);         CHUNK16(la, hb, 2); }
    { DECL16(lb); GLOAD16(lb, wlds + 32768 + t*8); CHUNK16(lb, hb, 3); }
    GLOAD16(sb, wt5);
    CHUNK16(sa, hb, 4);
    GLOAD16(sa, wt6);
    CHUNK16(sb, hb, 5);
    GLOAD16(sb, wt7);
    CHUNK16(sa, hb, 6);
    CHUNK16(sb, hb, 7);
    float ii = sigm_fast(acc[0] + xv[0]), ff = sigm_fast(acc[1] + xv[1]);
    float gg = tanh_fast(acc[2] + xv[2]), oo = sigm_fast(acc[3] + xv[3]);
    c0 = ff*c0 + ii*gg;
    float h0 = oo*tanh_fast(c0); sum0 += h0;
    hbuf[cur ^ 1][t] = (f16)h0;
    outp[(size_t)step*ostride] = (f16)h0;
    __syncthreads();
    cur ^= 1;
  }
  if (l == 2) g_feats[b*512 + 256 + t] = sum0*(1.0f/1024.0f);
}

// ---------------- generic fp16 MFMA GEMM (implicit conv / xg projection) ----
__global__ void __launch_bounds__(256) k_gemm(int which, int l,
                                              const float* cb, const float* bng, const float* bnb) {
  const f16* A; size_t a_bs; int a_rs, K, N; const f16* Bm; int mode;
  float* outF = nullptr; f16* outH = nullptr; size_t o_bs; int o_rs;
  const float* bias;
  if (which <= 1) {
    A = (which == 0) ? g_fseqA : g_fseqB; a_bs = 262144u; a_rs = 256; K = 256; N = 1024;
    Bm = g_wihB + (size_t)l*262144u; mode = 0; bias = g_biasP + l*1024;
    outF = g_xg32; o_bs = 1048576u; o_rs = 1024;
  } else if (which == 2) {
    A = g_Xpad; a_bs = 526336u; a_rs = 512; K = 2560; N = 256; Bm = g_B1; mode = 1; bias = cb;
    outH = g_c2in + 256; o_bs = 262656u; o_rs = 256;
  } else {
    A = g_c2in; a_bs = 262656u; a_rs = 256; K = 768; N = 128; Bm = g_B2; mode = 1; bias = cb;
    outH = g_c3in; o_bs = 131072u; o_rs = 128;
  }
  int tid = threadIdx.x, wave = tid >> 6, lane = tid & 63;
  int m0 = blockIdx.x*128, n0 = blockIdx.y*64;
  __shared__ __align__(16) f16 Asm[128*72];
  __shared__ __align__(16) f16 Bsm[64*72];
  f32x4 acc[2][4];
#pragma unroll
  for (int i = 0; i < 2; ++i)
#pragma unroll
    for (int j = 0; j < 4; ++j) { f32x4 zz = {0.f,0.f,0.f,0.f}; acc[i][j] = zz; }
  int ar = tid & 127, ac = (tid >> 7)*32;
  int mrow = m0 + ar, abb = mrow >> 10, att = mrow & 1023;
  const f16* aptr = A + (size_t)abb*a_bs + (size_t)att*a_rs + ac;
  int br = tid & 63, bc = (tid >> 6)*16;
  const f16* bptr = Bm + (size_t)(n0 + br)*K + bc;
  int nkb = K >> 6;
  for (int kb = 0; kb < nkb; ++kb) {
    f16x8 av0 = *(const f16x8*)(aptr + 0);
    f16x8 av1 = *(const f16x8*)(aptr + 8);
    f16x8 av2 = *(const f16x8*)(aptr + 16);
    f16x8 av3 = *(const f16x8*)(aptr + 24);
    f16x8 bv0 = *(const f16x8*)(bptr + 0);
    f16x8 bv1 = *(const f16x8*)(bptr + 8);
    aptr += 64; bptr += 64;
    __syncthreads();
    *(f16x8*)(&Asm[ar*72 + ac + 0])  = av0;
    *(f16x8*)(&Asm[ar*72 + ac + 8])  = av1;
    *(f16x8*)(&Asm[ar*72 + ac + 16]) = av2;
    *(f16x8*)(&Asm[ar*72 + ac + 24]) = av3;
    *(f16x8*)(&Bsm[br*72 + bc + 0])  = bv0;
    *(f16x8*)(&Bsm[br*72 + bc + 8])  = bv1;
    __syncthreads();
#pragma unroll
    for (int ks = 0; ks < 2; ++ks) {
      int ko = ks*32 + (lane >> 4)*8;
      f16x8 a0 = *(const f16x8*)(&Asm[(wave*32 + (lane & 15))*72 + ko]);
      f16x8 a1 = *(const f16x8*)(&Asm[(wave*32 + 16 + (lane & 15))*72 + ko]);
#pragma unroll
      for (int nt = 0; nt < 4; ++nt) {
        f16x8 bf = *(const f16x8*)(&Bsm[(nt*16 + (lane & 15))*72 + ko]);
        acc[0][nt] = __builtin_amdgcn_mfma_f32_16x16x32_f16(a0, bf, acc[0][nt], 0, 0, 0);
        acc[1][nt] = __builtin_amdgcn_mfma_f32_16x16x32_f16(a1, bf, acc[1][nt], 0, 0, 0);
      }
    }
  }
  const float bnc = 0.99999500003749969f;  // 1/sqrt(1+1e-5)
#pragma unroll
  for (int mt = 0; mt < 2; ++mt)
#pragma unroll
    for (int nt = 0; nt < 4; ++nt)
#pragma unroll
      for (int r = 0; r < 4; ++r) {
        int m_loc = wave*32 + mt*16 + (lane >> 4)*4 + r;
        int n = n0 + nt*16 + (lane & 15);
        int mg = m0 + m_loc, ob = mg >> 10, ot = mg & 1023;
        float v = acc[mt][nt][r];
        if (mode == 0) {
          v += bias[n];
          outF[(size_t)ob*o_bs + (size_t)ot*o_rs + n] = v;
        } else {
          v = (v + bias[n])*(bng[n]*bnc) + bnb[n];
          v = lrelu(v);
          outH[(size_t)ob*o_bs + (size_t)ot*o_rs + n] = (f16)v;
        }
      }
}

// ---------------- cp head / cardiac params ----------------------------------
__global__ void __launch_bounds__(128) k_cp(const float* w1, const float* b1v, const float* lg,
                                            const float* lb, const float* w2, const float* b2v) {
  __shared__ float ft[512], av[128], s1[128], s2[128];
  int b = blockIdx.x, tid = threadIdx.x;
  for (int i = tid; i < 512; i += 128) ft[i] = g_feats[b*512 + i];
  __syncthreads();
  float acc = b1v[tid];
  for (int k = 0; k < 512; ++k) acc += w1[tid*512 + k]*ft[k];
  s1[tid] = acc; s2[tid] = acc*acc; __syncthreads();
  for (int s = 64; s > 0; s >>= 1) { if (tid < s) { s1[tid]+=s1[tid+s]; s2[tid]+=s2[tid+s]; } __syncthreads(); }
  float m = s1[0]*(1.0f/128.0f), var = s2[0]*(1.0f/128.0f) - m*m;
  av[tid] = lrelu((acc - m)*(1.0f/sqrtf(var + 1e-5f))*lg[tid] + lb[tid]);
  __syncthreads();
  if (tid < 4) {
    float s = b2v[tid];
    for (int i = 0; i < 128; ++i) s += w2[tid*128 + i]*av[i];
    g_cpar[b*4 + tid] = 1.0f/(1.0f + expf(-s));
  }
}

// ---------------- conv3 + enhanced ------------------------------------------
__global__ void __launch_bounds__(256) k_enh(const float* w3, const float* b3) {
  int idx = blockIdx.x*256 + threadIdx.x;
  int b = idx >> 10, t = idx & 1023;
  const f16* xc = g_c3in + (size_t)idx*128u;
  bool hm = (t > 0), hp = (t < 1023);
  float pre = b3[0];
  for (int c = 0; c < 128; ++c) {
    float xm = hm ? (float)xc[c - 128] : 0.0f;
    float x0 = (float)xc[c];
    float xp = hp ? (float)xc[c + 128] : 0.0f;
    pre += xm*w3[c*3] + x0*w3[c*3 + 1] + xp*w3[c*3 + 2];
  }
  float base = tanhf(pre);
  float cp0 = g_cpar[b*4 + 0], cp1 = g_cpar[b*4 + 1], cp2 = g_cpar[b*4 + 2], cp3 = g_cpar[b*4 + 3];
  float freq  = 0.19f + 0.1f*cp0;
  float amp   = 1.0f + 2.0f*cp1;
  float phase = 6.2831853071795864f*cp2;
  float basel = -0.5f + cp3;
  float tl = t*(1.0f/1023.0f);
  float arg = ((6.2831853071795864f*freq)*1024.0f)*tl + phase;
  float card = amp*sinf(arg) + basel;
  g_enh[idx] = 0.1f*base + 0.1f*g_osc[idx] + 0.7f*card + 0.1f*g_smean[t];
}

__global__ void __launch_bounds__(256) k_out(const int* labels, const float* sw,
                                             const float* aw, const float* ab, float* out) {
  int idx = blockIdx.x*256 + threadIdx.x;
  int b = idx >> 10, t = idx & 1023;
  int lab = labels[b];
  float e = g_enh[idx], r;
  if (lab == 1) r = e;
  else if (lab == 2) r = sw[0]*e;
  else if (lab == 3) {
    float em = (t > 0)    ? g_enh[idx - 1] : 0.0f;
    float ep = (t < 1023) ? g_enh[idx + 1] : 0.0f;
    r = aw[0]*em + aw[1]*e + aw[2]*ep + ab[0];
  } else r = 0.0f;
  out[idx] = r;
}

// ---------------- launch -----------------------------------------------------
extern "C" void kernel_launch(void* const* d_in, const int* in_sizes, int n_in,
                              void* d_out, int out_size, void* d_ws, size_t ws_size,
                              hipStream_t stream) {
  const float* z       = (const float*)d_in[0];
  const int*   labels  = (const int*)  d_in[1];
  const float* emb     = (const float*)d_in[2];
  const float* np_w    = (const float*)d_in[3];
  const float* np_b    = (const float*)d_in[4];
  const float* np_ln_g = (const float*)d_in[5];
  const float* np_ln_b = (const float*)d_in[6];
  const float* c_wih   = (const float*)d_in[7];
  const float* c_whh   = (const float*)d_in[8];
  const float* c_bih   = (const float*)d_in[9];
  const float* c_bhh   = (const float*)d_in[10];
  const float* f0_wih  = (const float*)d_in[11];
  const float* f0_whh  = (const float*)d_in[12];
  const float* f0_bih  = (const float*)d_in[13];
  const float* f0_bhh  = (const float*)d_in[14];
  const float* f_wih   = (const float*)d_in[15];
  const float* f_whh   = (const float*)d_in[16];
  const float* f_bih   = (const float*)d_in[17];
  const float* f_bhh   = (const float*)d_in[18];
  const float* osc_w1  = (const float*)d_in[19];
  const float* osc_b1  = (const float*)d_in[20];
  const float* osc_ln_g= (const float*)d_in[21];
  const float* osc_ln_b= (const float*)d_in[22];
  const float* osc_w2  = (const float*)d_in[23];
  const float* osc_b2  = (const float*)d_in[24];
  const float* cp_w1   = (const float*)d_in[25];
  const float* cp_b1   = (const float*)d_in[26];
  const float* cp_ln_g = (const float*)d_in[27];
  const float* cp_ln_b = (const float*)d_in[28];
  const float* cp_w2   = (const float*)d_in[29];
  const float* cp_b2   = (const float*)d_in[30];
  const float* sin_w   = (const float*)d_in[31];
  const float* sin_b   = (const float*)d_in[32];
  const float* conv1_w = (const float*)d_in[33];
  const float* conv1_b = (const float*)d_in[34];
  const float* bn1_g   = (const float*)d_in[35];
  const float* bn1_b   = (const float*)d_in[36];
  const float* conv2_w = (const float*)d_in[37];
  const float* conv2_b = (const float*)d_in[38];
  const float* bn2_g   = (const float*)d_in[39];
  const float* bn2_b   = (const float*)d_in[40];
  const float* conv3_w = (const float*)d_in[41];
  const float* conv3_b = (const float*)d_in[42];
  const float* stress_w= (const float*)d_in[43];
  const float* amuse_w = (const float*)d_in[44];
  const float* amuse_b = (const float*)d_in[45];
  float* out = (float*)d_out;

  k_prep_whh<<<5120, 256, 0, stream>>>(c_whh, f0_whh, f_whh);
  k_prep_wih<<<3072, 256, 0, stream>>>(f_wih, f_bih, f_bhh);
  k_prep_c1 <<<2560, 256, 0, stream>>>(conv1_w);
  k_prep_c2 <<< 384, 256, 0, stream>>>(conv2_w);
  k_zero    <<< 640, 256, 0, stream>>>();
  k_setup1  <<<  64, 256, 0, stream>>>(z, labels, emb, np_w, np_b, np_ln_g, np_ln_b);
  k_xg0     <<< 128,1024, 0, stream>>>(c_wih, c_bih, c_bhh, f0_wih, f0_bih, f0_bhh);
  k_osc     <<<  64, 256, 0, stream>>>(osc_w1, osc_b1, osc_ln_g, osc_ln_b, osc_w2, osc_b2);
  k_sinmean <<<   4, 256, 0, stream>>>(sin_w, sin_b);

  k_lstmA   <<< 128, 256, 0, stream>>>();                       // coarse + f0 concurrently
  for (int l = 0; l < 3; ++l) {                                 // f1, f2, f3
    int which = (l == 1) ? 1 : 0;                               // input seq ping-pong
    k_gemm  <<<dim3(512,16), 256, 0, stream>>>(which, l, nullptr, nullptr, nullptr);
    k_lstmF <<<  64, 256, 0, stream>>>(l);
  }
  k_cp      <<<  64, 128, 0, stream>>>(cp_w1, cp_b1, cp_ln_g, cp_ln_b, cp_w2, cp_b2);
  k_gemm    <<<dim3(512, 4), 256, 0, stream>>>(2, 0, conv1_b, bn1_g, bn1_b);   // conv1
  k_gemm    <<<dim3(512, 2), 256, 0, stream>>>(3, 0, conv2_b, bn2_g, bn2_b);   // conv2
  k_enh     <<< 256, 256, 0, stream>>>(conv3_w, conv3_b);
  k_out     <<< 256, 256, 0, stream>>>(labels, stress_w, amuse_w, amuse_b, out);
}

// Round 8
// 16487.509 us; speedup vs baseline: 6.9282x; 2.3517x over previous
//
#include <hip/hip_runtime.h>

typedef _Float16 f16;
typedef _Float16 f16x2 __attribute__((ext_vector_type(2)));
typedef _Float16 f16x8 __attribute__((ext_vector_type(8)));
typedef float    f32x4 __attribute__((ext_vector_type(4)));

// ---------------- static device scratch (avoids ws_size assumptions) --------
__device__ f16   g_Xpad [64u*1028u*512u];   // conv1 input (B,T+4,512): ch0-255 coarse, 256-511 fine(final)
__device__ f16   g_fseqA[64u*1024u*256u];   // fine sequence ping
__device__ f16   g_fseqB[64u*1024u*256u];   // fine sequence pong
__device__ float g_xg32 [64u*1024u*1024u];  // per-f-layer input projection, permuted gate order, fp32
__device__ f16   g_c2in [64u*1026u*256u];   // conv2 input (B,T+2,256), padded
__device__ f16   g_c3in [64u*1024u*128u];   // conv3 input (B,T,128)
// whh octet-major layout: [L][ko:32][r:1024][kl:8]; k = ko*8+kl, r = u*4+q (orig row g=q*256+u)
__device__ f16   g_whhT2[5u*262144u];
__device__ f16   g_wihB [3u*262144u];       // [l][g'][k] fp16, permuted gate rows (g' = u*4+q)
__device__ float g_biasP[3*1024];           // permuted bih+bhh for f1..f3
__device__ f16   g_B1   [256u*2560u];       // conv1 weight as GEMM B [oc][r*512+ic]
__device__ f16   g_B2   [128u*768u];        // conv2 weight as GEMM B [oc][r*256+ic]
__device__ float g_xg0  [2*64*1024];        // static xg for coarse/f0, permuted [u*4+q]
__device__ float g_cat512[64*512];          // [h, le]
__device__ float g_h    [64*256];
__device__ float g_feats[64*512];           // [coarse.mean, fine.mean]
__device__ float g_osc  [64*1024];
__device__ float g_smean[1024];
__device__ float g_cpar [64*4];             // raw cp sigmoid outputs
__device__ float g_enh  [64*1024];

// ---------------- helpers ---------------------------------------------------
__device__ inline float fdot2f(f16x2 a, f16x2 b, float c) {
#if __has_builtin(__builtin_amdgcn_fdot2)
  return __builtin_amdgcn_fdot2(a, b, c, false);
#else
  return c + (float)a[0]*(float)b[0] + (float)a[1]*(float)b[1];
#endif
}
__device__ inline float sigm_fast(float x) { return 1.0f / (1.0f + __expf(-x)); }
__device__ inline float tanh_fast(float x) { float e = __expf(2.0f*x); return 1.0f - 2.0f/(e + 1.0f); }
__device__ inline float lrelu(float x) { return x < 0.0f ? 0.2f*x : x; }

__device__ __forceinline__ void dot8x(f16x8 w, f16x8 h, float& a) {
  a = fdot2f(__builtin_shufflevector(w, w, 0, 1), __builtin_shufflevector(h, h, 0, 1), a);
  a = fdot2f(__builtin_shufflevector(w, w, 2, 3), __builtin_shufflevector(h, h, 2, 3), a);
  a = fdot2f(__builtin_shufflevector(w, w, 4, 5), __builtin_shufflevector(h, h, 4, 5), a);
  a = fdot2f(__builtin_shufflevector(w, w, 6, 7), __builtin_shufflevector(h, h, 6, 7), a);
}

// Streamed weight group: 8 k-octets x 2 rows (tau, tau+512). All values are
// short-lived within one step -- no loop-carried register residency (the thing
// the compiler defeated in R2/R4/R6/R7). Plain loads, perfectly coalesced
// (consecutive lanes -> consecutive 16B in the [ko][r][8] layout).
#define SDECL(g) f16x8 g##a0,g##a1,g##a2,g##a3,g##a4,g##a5,g##a6,g##a7, \
                       g##b0,g##b1,g##b2,g##b3,g##b4,g##b5,g##b6,g##b7
#define SLOAD(g, base) do { const f16* _bp = (base); \
  g##a0 = *(const f16x8*)(_bp + 0*8192); g##b0 = *(const f16x8*)(_bp + 0*8192 + 4096); \
  g##a1 = *(const f16x8*)(_bp + 1*8192); g##b1 = *(const f16x8*)(_bp + 1*8192 + 4096); \
  g##a2 = *(const f16x8*)(_bp + 2*8192); g##b2 = *(const f16x8*)(_bp + 2*8192 + 4096); \
  g##a3 = *(const f16x8*)(_bp + 3*8192); g##b3 = *(const f16x8*)(_bp + 3*8192 + 4096); \
  g##a4 = *(const f16x8*)(_bp + 4*8192); g##b4 = *(const f16x8*)(_bp + 4*8192 + 4096); \
  g##a5 = *(const f16x8*)(_bp + 5*8192); g##b5 = *(const f16x8*)(_bp + 5*8192 + 4096); \
  g##a6 = *(const f16x8*)(_bp + 6*8192); g##b6 = *(const f16x8*)(_bp + 6*8192 + 4096); \
  g##a7 = *(const f16x8*)(_bp + 7*8192); g##b7 = *(const f16x8*)(_bp + 7*8192 + 4096); } while (0)
#define SDOT(g, hbp, kob) do { f16x8 _h; \
  _h = *(const f16x8*)((hbp) + ((kob)+0)*8); dot8x(g##a0,_h,accA); dot8x(g##b0,_h,accB); \
  _h = *(const f16x8*)((hbp) + ((kob)+1)*8); dot8x(g##a1,_h,accA); dot8x(g##b1,_h,accB); \
  _h = *(const f16x8*)((hbp) + ((kob)+2)*8); dot8x(g##a2,_h,accA); dot8x(g##b2,_h,accB); \
  _h = *(const f16x8*)((hbp) + ((kob)+3)*8); dot8x(g##a3,_h,accA); dot8x(g##b3,_h,accB); \
  _h = *(const f16x8*)((hbp) + ((kob)+4)*8); dot8x(g##a4,_h,accA); dot8x(g##b4,_h,accB); \
  _h = *(const f16x8*)((hbp) + ((kob)+5)*8); dot8x(g##a5,_h,accA); dot8x(g##b5,_h,accB); \
  _h = *(const f16x8*)((hbp) + ((kob)+6)*8); dot8x(g##a6,_h,accA); dot8x(g##b6,_h,accB); \
  _h = *(const f16x8*)((hbp) + ((kob)+7)*8); dot8x(g##a7,_h,accA); dot8x(g##b7,_h,accB); } while (0)

// ---------------- weight prep ----------------------------------------------
__global__ void __launch_bounds__(256) k_prep_whh(const float* cw, const float* f0w, const float* fw) {
  int bid = blockIdx.x;               // 5*1024
  int L = bid >> 10, g = bid & 1023, k = threadIdx.x;
  const float* src = (L == 0) ? cw : (L == 1) ? f0w : (fw + (size_t)(L-2)*262144u);
  int q = g >> 8, u = g & 255, r = u*4 + q;
  int ko = k >> 3, kl = k & 7;
  g_whhT2[(size_t)L*262144u + (size_t)(ko*1024 + r)*8u + kl] = (f16)src[(size_t)g*256 + k];
}
__global__ void __launch_bounds__(256) k_prep_wih(const float* fwih, const float* fbih, const float* fbhh) {
  int bid = blockIdx.x;               // 3*1024
  int L = bid >> 10, gp = bid & 1023, k = threadIdx.x;
  int j = gp >> 2, q = gp & 3, g = q*256 + j;
  g_wihB[(size_t)L*262144u + (size_t)gp*256u + k] = (f16)fwih[(size_t)L*262144u + (size_t)g*256u + k];
  if (k == 0) g_biasP[L*1024 + gp] = fbih[L*1024 + g] + fbhh[L*1024 + g];
}
__global__ void __launch_bounds__(256) k_prep_c1(const float* w) {
  int idx = blockIdx.x*256 + threadIdx.x;        // 655360
  int oc = idx / 2560, rem = idx % 2560, r = rem / 512, ic = rem % 512;
  g_B1[idx] = (f16)w[(size_t)oc*2560 + (size_t)ic*5 + r];
}
__global__ void __launch_bounds__(256) k_prep_c2(const float* w) {
  int idx = blockIdx.x*256 + threadIdx.x;        // 98304
  int oc = idx / 768, rem = idx % 768, r = rem / 256, ic = rem % 256;
  g_B2[idx] = (f16)w[(size_t)oc*768 + (size_t)ic*3 + r];
}
__global__ void __launch_bounds__(256) k_zero() {
  int idx = blockIdx.x*256 + threadIdx.x;        // 163840
  if (idx < 131072) {   // Xpad pad rows 0,1,1026,1027
    int b = idx >> 11, rem = idx & 2047, rr = rem >> 9, c = rem & 511;
    int row = (rr < 2) ? rr : 1024 + rr;
    g_Xpad[(size_t)b*526336u + (size_t)row*512u + c] = (f16)0.0f;
  } else {              // c2in pad rows 0, 1025
    int i2 = idx - 131072;
    int b = i2 >> 9, rem = i2 & 511, rr = rem >> 8, c = rem & 255;
    int row = rr ? 1025 : 0;
    g_c2in[(size_t)b*262656u + (size_t)row*256u + c] = (f16)0.0f;
  }
}

// ---------------- small front-end ops ---------------------------------------
__global__ void __launch_bounds__(256) k_setup1(const float* z, const int* labels, const float* emb,
                                                const float* npw, const float* npb,
                                                const float* lg, const float* lb) {
  __shared__ float x[384];
  __shared__ float s1[256], s2[256];
  int b = blockIdx.x, tid = threadIdx.x;
  int lab = labels[b];
  for (int i = tid; i < 384; i += 256)
    x[i] = (i < 128) ? z[b*128 + i] : emb[lab*256 + (i - 128)];
  __syncthreads();
  float acc = npb[tid];
  for (int k = 0; k < 384; ++k) acc += npw[tid*384 + k]*x[k];
  s1[tid] = acc; s2[tid] = acc*acc; __syncthreads();
  for (int s = 128; s > 0; s >>= 1) { if (tid < s) { s1[tid]+=s1[tid+s]; s2[tid]+=s2[tid+s]; } __syncthreads(); }
  float m = s1[0]*(1.0f/256.0f), var = s2[0]*(1.0f/256.0f) - m*m;
  float hv = (acc - m)*(1.0f/sqrtf(var + 1e-5f))*lg[tid] + lb[tid];
  hv = lrelu(hv);
  g_h[b*256 + tid] = hv;
  g_cat512[b*512 + tid] = hv;
  g_cat512[b*512 + 256 + tid] = x[128 + tid];
}
__global__ void __launch_bounds__(1024) k_xg0(const float* cwih, const float* cbih, const float* cbhh,
                                              const float* fwih, const float* fbih, const float* fbhh) {
  int bid = blockIdx.x;               // 128 = layer*64+b
  int layer = bid >> 6, b = bid & 63;
  int gp = threadIdx.x, j = gp >> 2, q = gp & 3, g = q*256 + j;
  __shared__ float cat[512];
  if (gp < 512) cat[gp] = g_cat512[b*512 + gp];
  __syncthreads();
  const float* w = layer ? fwih : cwih;
  float acc = layer ? (fbih[g] + fbhh[g]) : (cbih[g] + cbhh[g]);
  for (int k = 0; k < 512; ++k) acc += w[(size_t)g*512 + k]*cat[k];
  g_xg0[(layer*64 + b)*1024 + gp] = acc;
}
__global__ void __launch_bounds__(256) k_osc(const float* w1, const float* b1v, const float* lg,
                                             const float* lb, const float* w2, const float* b2v) {
  __shared__ float hb[256], av[256], s1[256], s2[256];
  int b = blockIdx.x, tid = threadIdx.x;
  hb[tid] = g_h[b*256 + tid];
  __syncthreads();
  float acc = b1v[tid];
  for (int k = 0; k < 256; ++k) acc += w1[tid*256 + k]*hb[k];
  s1[tid] = acc; s2[tid] = acc*acc; __syncthreads();
  for (int s = 128; s > 0; s >>= 1) { if (tid < s) { s1[tid]+=s1[tid+s]; s2[tid]+=s2[tid+s]; } __syncthreads(); }
  float m = s1[0]*(1.0f/256.0f), var = s2[0]*(1.0f/256.0f) - m*m;
  av[tid] = lrelu((acc - m)*(1.0f/sqrtf(var + 1e-5f))*lg[tid] + lb[tid]);
  __syncthreads();
  for (int tt = tid; tt < 1024; tt += 256) {
    float o = b2v[tt];
    for (int i = 0; i < 256; ++i) o += w2[(size_t)tt*256 + i]*av[i];
    g_osc[b*1024 + tt] = tanhf(o);
  }
}
__global__ void __launch_bounds__(256) k_sinmean(const float* sw, const float* sb) {
  int tt = blockIdx.x*256 + threadIdx.x;   // grid 4
  const float F[6] = {0.19f, 0.21f, 0.23f, 0.25f, 0.27f, 0.29f};
  float tl = tt*(1.0f/1023.0f);
  float sc[12];
  for (int j = 0; j < 6; ++j) {
    float p = (6.2831853071795864f * tl) * F[j] * 1024.0f;
    sc[j] = sinf(p); sc[6 + j] = cosf(p);
  }
  float a = 0.0f;
  for (int i = 0; i < 128; ++i) {
    float s = sb[i];
    for (int j = 0; j < 12; ++j) s += sw[i*12 + j]*sc[j];
    a += s;
  }
  g_smean[tt] = a*(1.0f/128.0f);
}

// ---------------- LSTM core (1 batch / block, 512 threads = 8 waves/CU) -----
// Thread tau owns permuted gate rows tau and tau+512. Weights [ko][r][8]:
//   ko 0..7  (128 KB) LDS-resident, copied once (proven mechanism)
//   ko 8..31 (384 KB) streamed per step, 3 groups interleaved with compute;
//            ALL streamed values are short-lived (no loop-carried registers
//            for the compiler to demote -- the R2/R4/R6/R7 lesson).
// h broadcast via LDS octets; gates exchanged via gbuf; update on threads<256.
// 2 barriers/step. 8 waves/CU (2/SIMD) hide the L2 stream latency that capped
// R4 (4 waves, 1/SIMD). Per-CU port floor: 384KB/step @ ~60B/cy ~= 6.4K cy.
__global__ void __launch_bounds__(512, 1) k_lstmA() {
  int bid = blockIdx.x;              // 128: [0,64) coarse, [64,128) f0
  int layer = bid >> 6, b = bid & 63;
  int tau = threadIdx.x;             // 0..511
  const f16* Wc = g_whhT2 + (size_t)layer*262144u;
  __shared__ __align__(16) f16 wlds[65536];      // ko 0..7: [ko][r][8]
  __shared__ __align__(16) f16 hbuf[2][256];
  __shared__ __align__(16) float gbuf[1024];
#pragma unroll
  for (int i = 0; i < 16; ++i) {                 // LDS <- first 128 KB
    int o = i*512 + tau;
    *(f16x8*)(wlds + (size_t)o*8u) = *(const f16x8*)(Wc + (size_t)o*8u);
  }
  const f16* sbase = Wc + (size_t)(8*1024 + tau)*8u;   // ko=8, row tau
  float c0 = 0.0f, sum0 = 0.0f;
  f32x4 xg = {0.f, 0.f, 0.f, 0.f};
  f16* outp = nullptr; int ostride = 0;
  if (tau < 256) {
    xg = *(const f32x4*)(g_xg0 + (layer*64 + b)*1024 + 4*tau);
    hbuf[0][tau] = (f16)0.0f;
    if (layer == 0) { outp = g_Xpad + (size_t)b*526336u + 1024 + tau; ostride = 512; }
    else            { outp = g_fseqA + (size_t)b*262144u + tau;       ostride = 256; }
  }
  __syncthreads();
  int cur = 0;
#pragma unroll 1
  for (int step = 0; step < 1024; ++step) {
    const f16* hb = &hbuf[cur][0];
    float accA = 0.0f, accB = 0.0f;
    SDECL(p); SDECL(q2);
    SLOAD(p, sbase);                               // ko 8..15 in flight
    // LDS-resident ko 0..7
#pragma unroll
    for (int ko = 0; ko < 8; ++ko) {
      f16x8 hv = *(const f16x8*)(hb + ko*8);
      f16x8 wA = *(const f16x8*)(wlds + (size_t)(ko*1024 + tau)*8u);
      f16x8 wB = *(const f16x8*)(wlds + (size_t)(ko*1024 + tau + 512)*8u);
      dot8x(wA, hv, accA); dot8x(wB, hv, accB);
    }
    SLOAD(q2, sbase + 8*8192);                     // ko 16..23 in flight
    SDOT(p, hb, 8);
    SLOAD(p, sbase + 16*8192);                     // ko 24..31 in flight
    SDOT(q2, hb, 16);
    SDOT(p, hb, 24);
    gbuf[tau] = accA; gbuf[tau + 512] = accB;
    __syncthreads();
    if (tau < 256) {
      f32x4 gv = *(const f32x4*)(&gbuf[4*tau]);
      float ii = sigm_fast(gv[0] + xg[0]), ff = sigm_fast(gv[1] + xg[1]);
      float gg = tanh_fast(gv[2] + xg[2]), oo = sigm_fast(gv[3] + xg[3]);
      c0 = ff*c0 + ii*gg;
      float h0 = oo*tanh_fast(c0); sum0 += h0;
      hbuf[cur ^ 1][tau] = (f16)h0;
      outp[(size_t)step*ostride] = (f16)h0;
    }
    __syncthreads();
    cur ^= 1;
  }
  if (tau < 256 && layer == 0) g_feats[b*512 + tau] = sum0*(1.0f/1024.0f);
}

__global__ void __launch_bounds__(512, 1) k_lstmF(int l) {   // l=0..2 -> fine layers f1..f3
  int b = blockIdx.x;               // 64
  int tau = threadIdx.x;            // 0..511
  const f16* Wc = g_whhT2 + (size_t)(2 + l)*262144u;
  __shared__ __align__(16) f16 wlds[65536];
  __shared__ __align__(16) f16 hbuf[2][256];
  __shared__ __align__(16) float gbuf[1024];
#pragma unroll
  for (int i = 0; i < 16; ++i) {
    int o = i*512 + tau;
    *(f16x8*)(wlds + (size_t)o*8u) = *(const f16x8*)(Wc + (size_t)o*8u);
  }
  const f16* sbase = Wc + (size_t)(8*1024 + tau)*8u;
  const f32x4* xp = (const f32x4*)(g_xg32 + (size_t)b*1048576u + 4*tau);  // tau<256
  float c0 = 0.0f, sum0 = 0.0f;
  f32x4 xv = {0.f, 0.f, 0.f, 0.f};
  f16* outp = nullptr; int ostride = 0;
  if (tau < 256) {
    xv = xp[0];
    hbuf[0][tau] = (f16)0.0f;
    if (l == 0)      { outp = g_fseqB + (size_t)b*262144u + tau; ostride = 256; }
    else if (l == 1) { outp = g_fseqA + (size_t)b*262144u + tau; ostride = 256; }
    else             { outp = g_Xpad + (size_t)b*526336u + 1024 + 256 + tau; ostride = 512; }
  }
  __syncthreads();
  int cur = 0;
#pragma unroll 1
  for (int step = 0; step < 1024; ++step) {
    const f16* hb = &hbuf[cur][0];
    float accA = 0.0f, accB = 0.0f;
    SDECL(p); SDECL(q2);
    SLOAD(p, sbase);
#pragma unroll
    for (int ko = 0; ko < 8; ++ko) {
      f16x8 hv = *(const f16x8*)(hb + ko*8);
      f16x8 wA = *(const f16x8*)(wlds + (size_t)(ko*1024 + tau)*8u);
      f16x8 wB = *(const f16x8*)(wlds + (size_t)(ko*1024 + tau + 512)*8u);
      dot8x(wA, hv, accA); dot8x(wB, hv, accB);
    }
    SLOAD(q2, sbase + 8*8192);
    SDOT(p, hb, 8);
    SLOAD(p, sbase + 16*8192);
    SDOT(q2, hb, 16);
    SDOT(p, hb, 24);
    gbuf[tau] = accA; gbuf[tau + 512] = accB;
    __syncthreads();
    if (tau < 256) {
      f32x4 gv = *(const f32x4*)(&gbuf[4*tau]);
      float ii = sigm_fast(gv[0] + xv[0]), ff = sigm_fast(gv[1] + xv[1]);
      float gg = tanh_fast(gv[2] + xv[2]), oo = sigm_fast(gv[3] + xv[3]);
      c0 = ff*c0 + ii*gg;
      float h0 = oo*tanh_fast(c0); sum0 += h0;
      hbuf[cur ^ 1][tau] = (f16)h0;
      outp[(size_t)step*ostride] = (f16)h0;
      if (step < 1023) xv = xp[(size_t)(step + 1)*256u];
    }
    __syncthreads();
    cur ^= 1;
  }
  if (tau < 256 && l == 2) g_feats[b*512 + 256 + tau] = sum0*(1.0f/1024.0f);
}

// ---------------- generic fp16 MFMA GEMM (implicit conv / xg projection) ----
__global__ void __launch_bounds__(256) k_gemm(int which, int l,
                                              const float* cb, const float* bng, const float* bnb) {
  const f16* A; size_t a_bs; int a_rs, K, N; const f16* Bm; int mode;
  float* outF = nullptr; f16* outH = nullptr; size_t o_bs; int o_rs;
  const float* bias;
  if (which <= 1) {
    A = (which == 0) ? g_fseqA : g_fseqB; a_bs = 262144u; a_rs = 256; K = 256; N = 1024;
    Bm = g_wihB + (size_t)l*262144u; mode = 0; bias = g_biasP + l*1024;
    outF = g_xg32; o_bs = 1048576u; o_rs = 1024;
  } else if (which == 2) {
    A = g_Xpad; a_bs = 526336u; a_rs = 512; K = 2560; N = 256; Bm = g_B1; mode = 1; bias = cb;
    outH = g_c2in + 256; o_bs = 262656u; o_rs = 256;
  } else {
    A = g_c2in; a_bs = 262656u; a_rs = 256; K = 768; N = 128; Bm = g_B2; mode = 1; bias = cb;
    outH = g_c3in; o_bs = 131072u; o_rs = 128;
  }
  int tid = threadIdx.x, wave = tid >> 6, lane = tid & 63;
  int m0 = blockIdx.x*128, n0 = blockIdx.y*64;
  __shared__ __align__(16) f16 Asm[128*72];
  __shared__ __align__(16) f16 Bsm[64*72];
  f32x4 acc[2][4];
#pragma unroll
  for (int i = 0; i < 2; ++i)
#pragma unroll
    for (int j = 0; j < 4; ++j) { f32x4 zz = {0.f,0.f,0.f,0.f}; acc[i][j] = zz; }
  int ar = tid & 127, ac = (tid >> 7)*32;
  int mrow = m0 + ar, abb = mrow >> 10, att = mrow & 1023;
  const f16* aptr = A + (size_t)abb*a_bs + (size_t)att*a_rs + ac;
  int br = tid & 63, bc = (tid >> 6)*16;
  const f16* bptr = Bm + (size_t)(n0 + br)*K + bc;
  int nkb = K >> 6;
  for (int kb = 0; kb < nkb; ++kb) {
    f16x8 av0 = *(const f16x8*)(aptr + 0);
    f16x8 av1 = *(const f16x8*)(aptr + 8);
    f16x8 av2 = *(const f16x8*)(aptr + 16);
    f16x8 av3 = *(const f16x8*)(aptr + 24);
    f16x8 bv0 = *(const f16x8*)(bptr + 0);
    f16x8 bv1 = *(const f16x8*)(bptr + 8);
    aptr += 64; bptr += 64;
    __syncthreads();
    *(f16x8*)(&Asm[ar*72 + ac + 0])  = av0;
    *(f16x8*)(&Asm[ar*72 + ac + 8])  = av1;
    *(f16x8*)(&Asm[ar*72 + ac + 16]) = av2;
    *(f16x8*)(&Asm[ar*72 + ac + 24]) = av3;
    *(f16x8*)(&Bsm[br*72 + bc + 0])  = bv0;
    *(f16x8*)(&Bsm[br*72 + bc + 8])  = bv1;
    __syncthreads();
#pragma unroll
    for (int ks = 0; ks < 2; ++ks) {
      int ko = ks*32 + (lane >> 4)*8;
      f16x8 a0 = *(const f16x8*)(&Asm[(wave*32 + (lane & 15))*72 + ko]);
      f16x8 a1 = *(const f16x8*)(&Asm[(wave*32 + 16 + (lane & 15))*72 + ko]);
#pragma unroll
      for (int nt = 0; nt < 4; ++nt) {
        f16x8 bf = *(const f16x8*)(&Bsm[(nt*16 + (lane & 15))*72 + ko]);
        acc[0][nt] = __builtin_amdgcn_mfma_f32_16x16x32_f16(a0, bf, acc[0][nt], 0, 0, 0);
        acc[1][nt] = __builtin_amdgcn_mfma_f32_16x16x32_f16(a1, bf, acc[1][nt], 0, 0, 0);
      }
    }
  }
  const float bnc = 0.99999500003749969f;  // 1/sqrt(1+1e-5)
#pragma unroll
  for (int mt = 0; mt < 2; ++mt)
#pragma unroll
    for (int nt = 0; nt < 4; ++nt)
#pragma unroll
      for (int r = 0; r < 4; ++r) {
        int m_loc = wave*32 + mt*16 + (lane >> 4)*4 + r;
        int n = n0 + nt*16 + (lane & 15);
        int mg = m0 + m_loc, ob = mg >> 10, ot = mg & 1023;
        float v = acc[mt][nt][r];
        if (mode == 0) {
          v += bias[n];
          outF[(size_t)ob*o_bs + (size_t)ot*o_rs + n] = v;
        } else {
          v = (v + bias[n])*(bng[n]*bnc) + bnb[n];
          v = lrelu(v);
          outH[(size_t)ob*o_bs + (size_t)ot*o_rs + n] = (f16)v;
        }
      }
}

// ---------------- cp head / cardiac params ----------------------------------
__global__ void __launch_bounds__(128) k_cp(const float* w1, const float* b1v, const float* lg,
                                            const float* lb, const float* w2, const float* b2v) {
  __shared__ float ft[512], av[128], s1[128], s2[128];
  int b = blockIdx.x, tid = threadIdx.x;
  for (int i = tid; i < 512; i += 128) ft[i] = g_feats[b*512 + i];
  __syncthreads();
  float acc = b1v[tid];
  for (int k = 0; k < 512; ++k) acc += w1[tid*512 + k]*ft[k];
  s1[tid] = acc; s2[tid] = acc*acc; __syncthreads();
  for (int s = 64; s > 0; s >>= 1) { if (tid < s) { s1[tid]+=s1[tid+s]; s2[tid]+=s2[tid+s]; } __syncthreads(); }
  float m = s1[0]*(1.0f/128.0f), var = s2[0]*(1.0f/128.0f) - m*m;
  av[tid] = lrelu((acc - m)*(1.0f/sqrtf(var + 1e-5f))*lg[tid] + lb[tid]);
  __syncthreads();
  if (tid < 4) {
    float s = b2v[tid];
    for (int i = 0; i < 128; ++i) s += w2[tid*128 + i]*av[i];
    g_cpar[b*4 + tid] = 1.0f/(1.0f + expf(-s));
  }
}

// ---------------- conv3 + enhanced ------------------------------------------
__global__ void __launch_bounds__(256) k_enh(const float* w3, const float* b3) {
  int idx = blockIdx.x*256 + threadIdx.x;
  int b = idx >> 10, t = idx & 1023;
  const f16* xc = g_c3in + (size_t)idx*128u;
  bool hm = (t > 0), hp = (t < 1023);
  float pre = b3[0];
  for (int c = 0; c < 128; ++c) {
    float xm = hm ? (float)xc[c - 128] : 0.0f;
    float x0 = (float)xc[c];
    float xp = hp ? (float)xc[c + 128] : 0.0f;
    pre += xm*w3[c*3] + x0*w3[c*3 + 1] + xp*w3[c*3 + 2];
  }
  float base = tanhf(pre);
  float cp0 = g_cpar[b*4 + 0], cp1 = g_cpar[b*4 + 1], cp2 = g_cpar[b*4 + 2], cp3 = g_cpar[b*4 + 3];
  float freq  = 0.19f + 0.1f*cp0;
  float amp   = 1.0f + 2.0f*cp1;
  float phase = 6.2831853071795864f*cp2;
  float basel = -0.5f + cp3;
  float tl = t*(1.0f/1023.0f);
  float arg = ((6.2831853071795864f*freq)*1024.0f)*tl + phase;
  float card = amp*sinf(arg) + basel;
  g_enh[idx] = 0.1f*base + 0.1f*g_osc[idx] + 0.7f*card + 0.1f*g_smean[t];
}

__global__ void __launch_bounds__(256) k_out(const int* labels, const float* sw,
                                             const float* aw, const float* ab, float* out) {
  int idx = blockIdx.x*256 + threadIdx.x;
  int b = idx >> 10, t = idx & 1023;
  int lab = labels[b];
  float e = g_enh[idx], r;
  if (lab == 1) r = e;
  else if (lab == 2) r = sw[0]*e;
  else if (lab == 3) {
    float em = (t > 0)    ? g_enh[idx - 1] : 0.0f;
    float ep = (t < 1023) ? g_enh[idx + 1] : 0.0f;
    r = aw[0]*em + aw[1]*e + aw[2]*ep + ab[0];
  } else r = 0.0f;
  out[idx] = r;
}

// ---------------- launch -----------------------------------------------------
extern "C" void kernel_launch(void* const* d_in, const int* in_sizes, int n_in,
                              void* d_out, int out_size, void* d_ws, size_t ws_size,
                              hipStream_t stream) {
  const float* z       = (const float*)d_in[0];
  const int*   labels  = (const int*)  d_in[1];
  const float* emb     = (const float*)d_in[2];
  const float* np_w    = (const float*)d_in[3];
  const float* np_b    = (const float*)d_in[4];
  const float* np_ln_g = (const float*)d_in[5];
  const float* np_ln_b = (const float*)d_in[6];
  const float* c_wih   = (const float*)d_in[7];
  const float* c_whh   = (const float*)d_in[8];
  const float* c_bih   = (const float*)d_in[9];
  const float* c_bhh   = (const float*)d_in[10];
  const float* f0_wih  = (const float*)d_in[11];
  const float* f0_whh  = (const float*)d_in[12];
  const float* f0_bih  = (const float*)d_in[13];
  const float* f0_bhh  = (const float*)d_in[14];
  const float* f_wih   = (const float*)d_in[15];
  const float* f_whh   = (const float*)d_in[16];
  const float* f_bih   = (const float*)d_in[17];
  const float* f_bhh   = (const float*)d_in[18];
  const float* osc_w1  = (const float*)d_in[19];
  const float* osc_b1  = (const float*)d_in[20];
  const float* osc_ln_g= (const float*)d_in[21];
  const float* osc_ln_b= (const float*)d_in[22];
  const float* osc_w2  = (const float*)d_in[23];
  const float* osc_b2  = (const float*)d_in[24];
  const float* cp_w1   = (const float*)d_in[25];
  const float* cp_b1   = (const float*)d_in[26];
  const float* cp_ln_g = (const float*)d_in[27];
  const float* cp_ln_b = (const float*)d_in[28];
  const float* cp_w2   = (const float*)d_in[29];
  const float* cp_b2   = (const float*)d_in[30];
  const float* sin_w   = (const float*)d_in[31];
  const float* sin_b   = (const float*)d_in[32];
  const float* conv1_w = (const float*)d_in[33];
  const float* conv1_b = (const float*)d_in[34];
  const float* bn1_g   = (const float*)d_in[35];
  const float* bn1_b   = (const float*)d_in[36];
  const float* conv2_w = (const float*)d_in[37];
  const float* conv2_b = (const float*)d_in[38];
  const float* bn2_g   = (const float*)d_in[39];
  const float* bn2_b   = (const float*)d_in[40];
  const float* conv3_w = (const float*)d_in[41];
  const float* conv3_b = (const float*)d_in[42];
  const float* stress_w= (const float*)d_in[43];
  const float* amuse_w = (const float*)d_in[44];
  const float* amuse_b = (const float*)d_in[45];
  float* out = (float*)d_out;

  k_prep_whh<<<5120, 256, 0, stream>>>(c_whh, f0_whh, f_whh);
  k_prep_wih<<<3072, 256, 0, stream>>>(f_wih, f_bih, f_bhh);
  k_prep_c1 <<<2560, 256, 0, stream>>>(conv1_w);
  k_prep_c2 <<< 384, 256, 0, stream>>>(conv2_w);
  k_zero    <<< 640, 256, 0, stream>>>();
  k_setup1  <<<  64, 256, 0, stream>>>(z, labels, emb, np_w, np_b, np_ln_g, np_ln_b);
  k_xg0     <<< 128,1024, 0, stream>>>(c_wih, c_bih, c_bhh, f0_wih, f0_bih, f0_bhh);
  k_osc     <<<  64, 256, 0, stream>>>(osc_w1, osc_b1, osc_ln_g, osc_ln_b, osc_w2, osc_b2);
  k_sinmean <<<   4, 256, 0, stream>>>(sin_w, sin_b);

  k_lstmA   <<< 128, 512, 0, stream>>>();                       // coarse + f0 concurrently
  for (int l = 0; l < 3; ++l) {                                 // f1, f2, f3
    int which = (l == 1) ? 1 : 0;                               // input seq ping-pong
    k_gemm  <<<dim3(512,16), 256, 0, stream>>>(which, l, nullptr, nullptr, nullptr);
    k_lstmF <<<  64, 512, 0, stream>>>(l);
  }
  k_cp      <<<  64, 128, 0, stream>>>(cp_w1, cp_b1, cp_ln_g, cp_ln_b, cp_w2, cp_b2);
  k_gemm    <<<dim3(512, 4), 256, 0, stream>>>(2, 0, conv1_b, bn1_g, bn1_b);   // conv1
  k_gemm    <<<dim3(512, 2), 256, 0, stream>>>(3, 0, conv2_b, bn2_g, bn2_b);   // conv2
  k_enh     <<< 256, 256, 0, stream>>>(conv3_w, conv3_b);
  k_out     <<< 256, 256, 0, stream>>>(labels, stress_w, amuse_w, amuse_b, out);
}